// Round 1
// baseline (4087.811 us; speedup 1.0000x reference)
//
#include <hip/hip_runtime.h>
#include <math.h>

#define SS 512
#define BB 64
#define II 512
#define HH 512
#define MM (SS*BB)

// ---------------------------------------------------------------------------
// Transpose W2 [H][H] -> W2T [k][j] so the recurrence streams coalesced.
// ---------------------------------------------------------------------------
__global__ __launch_bounds__(256) void k_transpose(const float* __restrict__ in,
                                                   float* __restrict__ out) {
    __shared__ float tile[32][33];
    const int tx = threadIdx.x, ty = threadIdx.y;
    int x = blockIdx.x * 32 + tx;
    int y = blockIdx.y * 32 + ty;
#pragma unroll
    for (int i = 0; i < 32; i += 8) tile[ty + i][tx] = in[(y + i) * HH + x];
    __syncthreads();
    x = blockIdx.y * 32 + tx;
    y = blockIdx.x * 32 + ty;
#pragma unroll
    for (int i = 0; i < 32; i += 8) out[(y + i) * HH + x] = tile[tx][ty + i];
}

// ---------------------------------------------------------------------------
// Input projection: C[m, j] = sum_k X[m,k] * W1[j,k] + b1[j]
// X: [M=S*B, K=512] row-major (x is [S,B,I] so m = s*B+b matches out layout)
// Tiled fp32 GEMM: 64x64 tile, BK=16, 256 threads, 4x4 per thread.
// Writes xp directly into d_out's h_seq region (consumed in place later).
// ---------------------------------------------------------------------------
__global__ __launch_bounds__(256) void k_ingemm(const float* __restrict__ X,
                                                const float* __restrict__ W1,
                                                const float* __restrict__ b1,
                                                float* __restrict__ C) {
    __shared__ float As[16][64];
    __shared__ float Bs[16][64];
    const int bm = blockIdx.x * 64, bn = blockIdx.y * 64;
    const int tid = threadIdx.x;
    const int tm = (tid >> 4) << 2, tn = (tid & 15) << 2;
    const int lr = tid >> 2, lq = (tid & 3) << 2;
    float acc[4][4] = {};
    const float* Xp = X + (size_t)(bm + lr) * II + lq;
    const float* Wp = W1 + (size_t)(bn + lr) * II + lq;
    for (int kb = 0; kb < II; kb += 16) {
        float4 a = *(const float4*)(Xp + kb);
        float4 w = *(const float4*)(Wp + kb);
        As[lq + 0][lr] = a.x; As[lq + 1][lr] = a.y;
        As[lq + 2][lr] = a.z; As[lq + 3][lr] = a.w;
        Bs[lq + 0][lr] = w.x; Bs[lq + 1][lr] = w.y;
        Bs[lq + 2][lr] = w.z; Bs[lq + 3][lr] = w.w;
        __syncthreads();
#pragma unroll
        for (int k = 0; k < 16; k++) {
            float4 av = *(const float4*)&As[k][tm];
            float4 bv = *(const float4*)&Bs[k][tn];
            float aa[4] = {av.x, av.y, av.z, av.w};
            float bb[4] = {bv.x, bv.y, bv.z, bv.w};
#pragma unroll
            for (int i = 0; i < 4; i++)
#pragma unroll
                for (int j = 0; j < 4; j++)
                    acc[i][j] = fmaf(aa[i], bb[j], acc[i][j]);
        }
        __syncthreads();
    }
#pragma unroll
    for (int i = 0; i < 4; i++) {
        float4 bv = *(const float4*)&b1[bn + tn];
        float4 o;
        o.x = acc[i][0] + bv.x; o.y = acc[i][1] + bv.y;
        o.z = acc[i][2] + bv.z; o.w = acc[i][3] + bv.w;
        *(float4*)&C[(size_t)(bm + tm + i) * HH + bn + tn] = o;
    }
}

// ---------------------------------------------------------------------------
// Recurrence: one workgroup per batch element (no cross-WG sync needed).
// h lives in LDS; W2T (1 MB) streamed from L2 each step.
// Thread t: kk = t>>7 selects contiguous k-chunk [kk*128, kk*128+128),
//           j4 = (t&127)*4 selects 4 output columns (float4 loads of W2T).
// 4 partial sums per column reduced through LDS, then tanh + in-place update.
// ---------------------------------------------------------------------------
__global__ __launch_bounds__(512) void k_rec(const float* __restrict__ w2t,
                                             const float* __restrict__ b2,
                                             float* __restrict__ out,
                                             float* __restrict__ hlast) {
    const int b = blockIdx.x;
    const int t = threadIdx.x;
    const int kk = t >> 7;
    const int j4 = (t & 127) << 2;
    __shared__ float h[HH];
    __shared__ float part[4][HH];
    h[t] = 0.0f;
    const float bias = b2[t];
    const float* wbase = w2t + (size_t)(kk << 7) * HH + j4;
    float* po = out + (size_t)b * HH + t;
    __syncthreads();
    for (int step = 0; step < SS; ++step) {
        float a0 = 0.f, a1 = 0.f, a2 = 0.f, a3 = 0.f;
        const float* wp = wbase;
        const float* hp = &h[kk << 7];
#pragma unroll 8
        for (int k = 0; k < 128; k++) {
            float hk = hp[k];
            float4 w = *(const float4*)wp;
            a0 = fmaf(w.x, hk, a0);
            a1 = fmaf(w.y, hk, a1);
            a2 = fmaf(w.z, hk, a2);
            a3 = fmaf(w.w, hk, a3);
            wp += HH;
        }
        *(float4*)&part[kk][j4] = make_float4(a0, a1, a2, a3);
        __syncthreads();
        float z = part[0][t] + part[1][t] + part[2][t] + part[3][t] + bias + *po;
        float hn = tanhf(z);
        *po = hn;
        h[t] = hn;
        po += BB * HH;
        __syncthreads();
    }
    hlast[(size_t)b * HH + t] = h[t];
}

extern "C" void kernel_launch(void* const* d_in, const int* in_sizes, int n_in,
                              void* d_out, int out_size, void* d_ws, size_t ws_size,
                              hipStream_t stream) {
    const float* x  = (const float*)d_in[0];
    const float* W1 = (const float*)d_in[1];
    const float* b1 = (const float*)d_in[2];
    const float* W2 = (const float*)d_in[3];
    const float* b2 = (const float*)d_in[4];
    float* out = (float*)d_out;
    float* w2t = (float*)d_ws;  // 512*512*4 = 1 MB scratch

    k_transpose<<<dim3(16, 16), dim3(32, 8), 0, stream>>>(W2, w2t);
    k_ingemm<<<dim3(MM / 64, HH / 64), 256, 0, stream>>>(x, W1, b1, out);
    k_rec<<<BB, 512, 0, stream>>>(w2t, b2, out, out + (size_t)SS * BB * HH);
}